// Round 5
// baseline (82.742 us; speedup 1.0000x reference)
//
#include <hip/hip_runtime.h>

// out[i][j] = A[i] * B[i][j], N = M = 8192, fp32.
// 2 rows per block, 256 threads: 16 float4 loads batched in flight
// (256 B/thread outstanding), then 16 non-temporal stores (output never
// re-read; keeps Infinity Cache for B's cross-replay retention).
// nt LOADS reverted: R4 showed FETCH_SIZE bit-identical -> MALL not steerable.

typedef float f32x4 __attribute__((ext_vector_type(4)));

#define M4 2048   // float4 per row (M = 8192)

__global__ __launch_bounds__(256) void scale_2rows_deep(
    const float* __restrict__ A,
    const f32x4* __restrict__ B4,
    f32x4* __restrict__ O4)
{
    const int row0 = blockIdx.x * 2;       // grid = 4096, 2 rows each
    const float a0 = A[row0];
    const float a1 = A[row0 + 1];
    const long base = (long)row0 * M4;
    const int t = threadIdx.x;

    f32x4 b[16];
    #pragma unroll
    for (int k = 0; k < 8; ++k)
        b[k] = B4[base + k * 256 + t];             // row0: 8 loads in flight
    #pragma unroll
    for (int k = 0; k < 8; ++k)
        b[8 + k] = B4[base + M4 + k * 256 + t];    // row1: 8 more in flight

    #pragma unroll
    for (int k = 0; k < 8; ++k)
        __builtin_nontemporal_store(a0 * b[k], &O4[base + k * 256 + t]);
    #pragma unroll
    for (int k = 0; k < 8; ++k)
        __builtin_nontemporal_store(a1 * b[8 + k], &O4[base + M4 + k * 256 + t]);
}

extern "C" void kernel_launch(void* const* d_in, const int* in_sizes, int n_in,
                              void* d_out, int out_size, void* d_ws, size_t ws_size,
                              hipStream_t stream) {
    const float* A = (const float*)d_in[0];      // (8192,)
    const f32x4* B4 = (const f32x4*)d_in[1];     // (8192, 8192) as float4
    f32x4* O4 = (f32x4*)d_out;

    const int N_BLOCKS = 4096;                   // 8192 rows / 2
    scale_2rows_deep<<<N_BLOCKS, 256, 0, stream>>>(A, B4, O4);
}